// Round 10
// baseline (514.549 us; speedup 1.0000x reference)
//
#include <hip/hip_runtime.h>
#include <hip/hip_bf16.h>

#define N_NODES 100000
#define NEDGE   600000
#define SCAN_B  1024
#define NBLK    98            // ceil(N_NODES / SCAN_B)
#define BSHIFT  9             // bucket = dst >> 9 (512 nodes/bucket)
#define NBUCK   196           // ceil(N_NODES / 512)
#define BCAP    3456          // per (rel,bucket) staging cap (mean 3061 + 7 sigma)

typedef __attribute__((ext_vector_type(8))) short bf16x8;
typedef __attribute__((ext_vector_type(4))) short s16x4;
typedef __attribute__((ext_vector_type(4))) float f32x4;
typedef __attribute__((ext_vector_type(4))) unsigned u32x4;

__device__ __forceinline__ short f2bf(float f) {
  union { float f; unsigned u; } x; x.f = f;
  unsigned r = x.u + 0x7FFFu + ((x.u >> 16) & 1u);
  return (short)(r >> 16);
}

// Phase A: bin edges into 196 per-bucket segments. Packed entry:
// bits 0..16 = src (max 99999 < 2^17), bits 17..25 = dst & 511.
__global__ __launch_bounds__(256) void bin_k(const int* __restrict__ sidx,
                                             const int* __restrict__ didx,
                                             int* __restrict__ bincnt,
                                             unsigned* __restrict__ stage) {
  __shared__ int hist[NBUCK];
  __shared__ int base[NBUCK];
  int r = blockIdx.y, t = threadIdx.x;
  int e0 = blockIdx.x * 2048 + t;
  const int* dd = didx + (size_t)r * NEDGE;
  const int* ss = sidx + (size_t)r * NEDGE;
  for (int i = t; i < NBUCK; i += 256) hist[i] = 0;
  __syncthreads();
  unsigned pv[8]; int bu[8], lr[8];
#pragma unroll
  for (int j = 0; j < 8; ++j) {
    int e = e0 + j * 256;
    if (e < NEDGE) {
      int dv = dd[e];
      bu[j] = dv >> BSHIFT;
      pv[j] = (unsigned)ss[e] | ((unsigned)(dv & 511) << 17);
      lr[j] = atomicAdd(&hist[bu[j]], 1);     // LDS atomic
    }
  }
  __syncthreads();
  for (int i = t; i < NBUCK; i += 256)
    base[i] = atomicAdd(&bincnt[r * NBUCK + i], hist[i]);
  __syncthreads();
#pragma unroll
  for (int j = 0; j < 8; ++j) {
    int e = e0 + j * 256;
    if (e < NEDGE)
      stage[(size_t)(r * NBUCK + bu[j]) * BCAP + base[bu[j]] + lr[j]] = pv[j];
  }
}

// Phase B: one block per (bucket, rel): LDS histogram, coalesced cnt write.
__global__ __launch_bounds__(256) void hist_k(const unsigned* __restrict__ stage,
                                              const int* __restrict__ bincnt,
                                              int* __restrict__ cnt) {
  __shared__ int h[512];
  int bu = blockIdx.x, r = blockIdx.y, t = threadIdx.x;
  int len = bincnt[r * NBUCK + bu];
  const unsigned* sg = stage + (size_t)(r * NBUCK + bu) * BCAP;
  h[t] = 0; h[t + 256] = 0;
  __syncthreads();
  for (int i = t; i < len; i += 256) atomicAdd(&h[sg[i] >> 17], 1);  // LDS
  __syncthreads();
  int lo = bu << BSHIFT;
  int d0 = lo + t;
  if (d0 < N_NODES)       cnt[r * N_NODES + d0]       = h[t];
  if (d0 + 256 < N_NODES) cnt[r * N_NODES + d0 + 256] = h[t + 256];
}

__global__ __launch_bounds__(256) void scan1_k(const int* __restrict__ cnt,
                                               int* __restrict__ bsum) {
  __shared__ int lds[256];
  int b = blockIdx.x, r = blockIdx.y, t = threadIdx.x;
  int i0 = b * SCAN_B + t * 4;
  int s = 0;
#pragma unroll
  for (int j = 0; j < 4; ++j)
    if (i0 + j < N_NODES) s += cnt[r * N_NODES + i0 + j];
  lds[t] = s;
  __syncthreads();
  for (int st = 128; st > 0; st >>= 1) {
    if (t < st) lds[t] += lds[t + st];
    __syncthreads();
  }
  if (t == 0) bsum[r * NBLK + b] = lds[0];
}

__global__ __launch_bounds__(128) void scan2_k(int* __restrict__ bsum) {
  __shared__ int buf[128];
  int t = threadIdx.x;
  for (int r = 0; r < 4; ++r) {
    int v = (t < NBLK) ? bsum[r * NBLK + t] : 0;
    buf[t] = v;
    __syncthreads();
    for (int st = 1; st < 128; st <<= 1) {
      int x = (t >= st) ? buf[t - st] : 0;
      __syncthreads();
      buf[t] += x;
      __syncthreads();
    }
    if (t < NBLK) bsum[r * NBLK + t] = buf[t] - v;   // exclusive
    __syncthreads();
  }
}

__global__ __launch_bounds__(256) void scan3_k(const int* __restrict__ cnt,
                                               const int* __restrict__ bsum,
                                               int* __restrict__ off) {
  __shared__ int lds[256];
  int b = blockIdx.x, r = blockIdx.y, t = threadIdx.x;
  int i0 = b * SCAN_B + t * 4;
  int c[4] = {0, 0, 0, 0};
#pragma unroll
  for (int j = 0; j < 4; ++j)
    if (i0 + j < N_NODES) c[j] = cnt[r * N_NODES + i0 + j];
  int s = c[0] + c[1] + c[2] + c[3];
  lds[t] = s;
  __syncthreads();
  for (int st = 1; st < 256; st <<= 1) {
    int x = (t >= st) ? lds[t - st] : 0;
    __syncthreads();
    lds[t] += x;
    __syncthreads();
  }
  int run = bsum[r * NBLK + b] + lds[t] - s;
  int* o = off + r * (N_NODES + 1);
#pragma unroll
  for (int j = 0; j < 4; ++j) {
    if (i0 + j < N_NODES) { o[i0 + j] = run; run += c[j]; }
  }
  if (b == 0 && t == 0) o[N_NODES] = NEDGE;
}

// Phase C: one block per (bucket, rel): place edges with LDS-only cursors.
__global__ __launch_bounds__(256) void place_k(const unsigned* __restrict__ stage,
                                               const int* __restrict__ bincnt,
                                               const int* __restrict__ off,
                                               int* __restrict__ csr) {
  __shared__ int ofl[512];
  __shared__ int cur[512];
  int bu = blockIdx.x, r = blockIdx.y, t = threadIdx.x;
  int len = bincnt[r * NBUCK + bu];
  const unsigned* sg = stage + (size_t)(r * NBUCK + bu) * BCAP;
  const int* of = off + r * (N_NODES + 1);
  int* cs = csr + (size_t)r * NEDGE;
  int lo = bu << BSHIFT;
  int d0 = lo + t;
  ofl[t]       = (d0 < N_NODES) ? of[d0] : 0;
  ofl[t + 256] = (d0 + 256 < N_NODES) ? of[d0 + 256] : 0;
  cur[t] = 0; cur[t + 256] = 0;
  __syncthreads();
  for (int i = t; i < len; i += 256) {
    unsigned v = sg[i];
    int dl = v >> 17;
    int pos = ofl[dl] + atomicAdd(&cur[dl], 1);   // LDS atomic
    cs[pos] = (int)(v & 0x1FFFFu);
  }
}

// f32 -> packed bf16 for both inputs in one dispatch (blockIdx.y selects).
__global__ __launch_bounds__(256) void cvt2_k(const float* __restrict__ x0,
                                              const float* __restrict__ x1,
                                              unsigned* __restrict__ o0,
                                              unsigned* __restrict__ o1) {
  const float* x = blockIdx.y ? x1 : x0;
  unsigned* o = blockIdx.y ? o1 : o0;
  int i = blockIdx.x * 256 + threadIdx.x;     // i < N_NODES*16
  if (i >= N_NODES * 16) return;
  f32x4 v0 = ((const f32x4*)x)[i * 2];
  f32x4 v1 = ((const f32x4*)x)[i * 2 + 1];
  unsigned r0 = (unsigned)(unsigned short)f2bf(v0[0]) |
                ((unsigned)(unsigned short)f2bf(v0[1]) << 16);
  unsigned r1 = (unsigned)(unsigned short)f2bf(v0[2]) |
                ((unsigned)(unsigned short)f2bf(v0[3]) << 16);
  unsigned r2 = (unsigned)(unsigned short)f2bf(v1[0]) |
                ((unsigned)(unsigned short)f2bf(v1[1]) << 16);
  unsigned r3 = (unsigned)(unsigned short)f2bf(v1[2]) |
                ((unsigned)(unsigned short)f2bf(v1[3]) << 16);
  ((u32x4*)o)[i] = (u32x4){r0, r1, r2, r3};
}

// Pack combined weights into MFMA B-fragment-linear layout.
__global__ __launch_bounds__(256) void prep_w_k(const float* __restrict__ Ws1,
                                                const float* __restrict__ Wn1,
                                                const float* __restrict__ Ws2,
                                                const float* __restrict__ Wn2,
                                                short* __restrict__ WTp) {
  int tid = blockIdx.x * 256 + threadIdx.x;  // 0..98303
  int lane = tid & 63;
  int n0 = (tid >> 6) & 7;
  int idx3 = tid >> 9;
  int k0 = idx3 % 12;
  int lt = idx3 / 12;
  int l = lt >> 1, t = lt & 1;
  const float* Wself  = l ? Ws2 : Ws1;
  const float* Wneigh = l ? Wn2 : Wn1;
  int rA = t ? 0 : 1, rB = t ? 3 : 2;
  int n = n0 * 16 + (lane & 15);
  int kbase = k0 * 32 + (lane >> 4) * 8;
  short out[8];
#pragma unroll
  for (int j = 0; j < 8; ++j) {
    int k = kbase + j;
    int kk = k & 127, blk = k >> 7;
    float v;
    if (blk == 0)      v = Wself[rA * 16384 + kk * 128 + n] + Wself[rB * 16384 + kk * 128 + n];
    else if (blk == 1) v = Wneigh[rA * 16384 + kk * 128 + n];
    else               v = Wneigh[rB * 16384 + kk * 128 + n];
    out[j] = f2bf(v);
  }
  s16x4* dst = (s16x4*)&WTp[tid * 8];
  dst[0] = *(s16x4*)&out[0];
  dst[1] = *(s16x4*)&out[4];
}

__global__ __launch_bounds__(256) void prep_b_k(const float* __restrict__ b1,
                                                const float* __restrict__ b2,
                                                float* __restrict__ biasc) {
  int tid = blockIdx.x * 256 + threadIdx.x;
  if (tid >= 512) return;
  int l = tid >> 8, t = (tid >> 7) & 1, c = tid & 127;
  const float* b = l ? b2 : b1;
  int rA = t ? 0 : 1, rB = t ? 3 : 2;
  biasc[tid] = b[rA * 128 + c] + b[rB * 128 + c];
}

#define ACC8(u, a)                                            \
  {                                                           \
    _Pragma("unroll") for (int q = 0; q < 4; ++q) {           \
      union { unsigned w; float f; } lo_, hi_;                \
      lo_.w = (u)[q] << 16; hi_.w = (u)[q] & 0xffff0000u;     \
      (a)[2 * q] += lo_.f; (a)[2 * q + 1] += hi_.f;           \
    }                                                         \
  }

__device__ __forceinline__ int clampi(int q, int p0, int p1) {
  int t = q < p1 ? q : p0;
  return t < NEDGE ? t : 0;
}

// One wave per node handling BOTH relations; both node types in one dispatch.
__global__ __launch_bounds__(256) void gather2_k(
    const unsigned* __restrict__ src0, const unsigned* __restrict__ src1,
    const int* __restrict__ csr, const int* __restrict__ off,
    unsigned* __restrict__ m00, unsigned* __restrict__ m01,
    unsigned* __restrict__ m10, unsigned* __restrict__ m11) {
  int wv = __builtin_amdgcn_readfirstlane(threadIdx.x >> 6);
  int wid = blockIdx.x * 4 + wv;          // 0 .. 2*N_NODES-1
  int lane = threadIdx.x & 63;
  int type = wid >= N_NODES;
  int n = type ? wid - N_NODES : wid;
  const unsigned* src = type ? src1 : src0;
  const int* csrA = csr + (type ? 0 : 1) * NEDGE;
  const int* csrB = csr + (type ? 3 : 2) * NEDGE;
  const int* offA = off + (type ? 0 : 1) * (N_NODES + 1);
  const int* offB = off + (type ? 3 : 2) * (N_NODES + 1);
  unsigned* mA = type ? m10 : m00;
  unsigned* mB = type ? m11 : m01;
  int pA0 = offA[n], pA1 = offA[n + 1];
  int pB0 = offB[n], pB1 = offB[n + 1];
  int degA = pA1 - pA0, degB = pB1 - pB0;
  int rowg = lane >> 4;          // 0..3: row within each quad
  int colg = lane & 15;          // 16B slice: u32s colg*4 .. colg*4+3
  float a[8] = {}, b[8] = {};
  // fast path: first 8 edges of each relation, all loads issued up front
  {
    int ia0 = csrA[clampi(pA0 + rowg,     pA0, pA1)];
    int ia1 = csrA[clampi(pA0 + 4 + rowg, pA0, pA1)];
    int ib0 = csrB[clampi(pB0 + rowg,     pB0, pB1)];
    int ib1 = csrB[clampi(pB0 + 4 + rowg, pB0, pB1)];
    u32x4 ua0 = *(const u32x4*)(src + (size_t)ia0 * 64 + colg * 4);
    u32x4 ua1 = *(const u32x4*)(src + (size_t)ia1 * 64 + colg * 4);
    u32x4 ub0 = *(const u32x4*)(src + (size_t)ib0 * 64 + colg * 4);
    u32x4 ub1 = *(const u32x4*)(src + (size_t)ib1 * 64 + colg * 4);
    if (pA0 + rowg     < pA1) ACC8(ua0, a);
    if (pA0 + 4 + rowg < pA1) ACC8(ua1, a);
    if (pB0 + rowg     < pB1) ACC8(ub0, b);
    if (pB0 + 4 + rowg < pB1) ACC8(ub1, b);
  }
  for (int p = pA0 + 8; p < pA1; p += 8) {
    int i0 = csrA[clampi(p + rowg,     pA0, pA1)];
    int i1 = csrA[clampi(p + 4 + rowg, pA0, pA1)];
    u32x4 u0 = *(const u32x4*)(src + (size_t)i0 * 64 + colg * 4);
    u32x4 u1 = *(const u32x4*)(src + (size_t)i1 * 64 + colg * 4);
    if (p + rowg     < pA1) ACC8(u0, a);
    if (p + 4 + rowg < pA1) ACC8(u1, a);
  }
  for (int p = pB0 + 8; p < pB1; p += 8) {
    int i0 = csrB[clampi(p + rowg,     pB0, pB1)];
    int i1 = csrB[clampi(p + 4 + rowg, pB0, pB1)];
    u32x4 u0 = *(const u32x4*)(src + (size_t)i0 * 64 + colg * 4);
    u32x4 u1 = *(const u32x4*)(src + (size_t)i1 * 64 + colg * 4);
    if (p + rowg     < pB1) ACC8(u0, b);
    if (p + 4 + rowg < pB1) ACC8(u1, b);
  }
#pragma unroll
  for (int q = 0; q < 8; ++q) {
    a[q] += __shfl_xor(a[q], 16); a[q] += __shfl_xor(a[q], 32);
    b[q] += __shfl_xor(b[q], 16); b[q] += __shfl_xor(b[q], 32);
  }
  if (rowg == 0) {
    float invA = 1.0f / (float)(degA > 1 ? degA : 1);
    float invB = 1.0f / (float)(degB > 1 ? degB : 1);
    u32x4 wa, wb;
#pragma unroll
    for (int q = 0; q < 4; ++q) {
      wa[q] = (unsigned)(unsigned short)f2bf(a[2 * q] * invA) |
              ((unsigned)(unsigned short)f2bf(a[2 * q + 1] * invA) << 16);
      wb[q] = (unsigned)(unsigned short)f2bf(b[2 * q] * invB) |
              ((unsigned)(unsigned short)f2bf(b[2 * q + 1] * invB) << 16);
    }
    // streaming stores: means are consumed once by the gemm; keep them out
    // of L2 so src rows stay resident.
    __builtin_nontemporal_store(wa, (u32x4*)(mA + (size_t)n * 64 + colg * 4));
    __builtin_nontemporal_store(wb, (u32x4*)(mB + (size_t)n * 64 + colg * 4));
  }
}

// Barrier-free GEMM: B-fragments read directly from global (L2-resident,
// 96KB/type shared by all blocks) -> no LDS staging, no __syncthreads,
// waves fully independent with ~10 loads in flight each.
template<int OUT_RELU_BF16>
__global__ __launch_bounds__(256) void gemm2_k(
    const short* __restrict__ self0, const short* __restrict__ self1,
    const short* __restrict__ mA0, const short* __restrict__ mB0,
    const short* __restrict__ mA1, const short* __restrict__ mB1,
    const short* __restrict__ WTpL, const float* __restrict__ biascL,
    void* __restrict__ out0, void* __restrict__ out1) {
  int type = blockIdx.y;
  const short* selfp = type ? self1 : self0;
  const short* meanA = type ? mA1 : mA0;
  const short* meanB = type ? mB1 : mB0;
  const short* WTp = WTpL + type * 49152;
  const float* biasc = biascL + type * 128;
  void* outp = type ? out1 : out0;
  int tid = threadIdx.x;
  int lane = tid & 63, wave = tid >> 6;
  int rowbase = blockIdx.x * 128 + wave * 32;
  int r0 = rowbase + (lane & 15), r1 = r0 + 16;
  int rc0 = r0 < N_NODES ? r0 : N_NODES - 1;
  int rc1 = r1 < N_NODES ? r1 : N_NODES - 1;
  int kg = lane >> 4;
  f32x4 acc[2][8] = {};
#pragma unroll 3
  for (int k0 = 0; k0 < 12; ++k0) {
    int kin = (k0 & 3) * 32 + kg * 8;
    const short* mp = (k0 < 4) ? selfp : ((k0 < 8) ? meanA : meanB);
    bf16x8 a0 = *(const bf16x8*)(mp + (size_t)rc0 * 128 + kin);
    bf16x8 a1 = *(const bf16x8*)(mp + (size_t)rc1 * 128 + kin);
    const short* wb = WTp + (size_t)k0 * 4096 + lane * 8;
#pragma unroll
    for (int n0 = 0; n0 < 8; ++n0) {
      bf16x8 b = *(const bf16x8*)(wb + n0 * 512);
      acc[0][n0] = __builtin_amdgcn_mfma_f32_16x16x32_bf16(a0, b, acc[0][n0], 0, 0, 0);
      acc[1][n0] = __builtin_amdgcn_mfma_f32_16x16x32_bf16(a1, b, acc[1][n0], 0, 0, 0);
    }
  }
  int colb = lane & 15, rloc = kg * 4;
#pragma unroll
  for (int mt = 0; mt < 2; ++mt) {
    int rb = rowbase + mt * 16 + rloc;
#pragma unroll
    for (int n0 = 0; n0 < 8; ++n0) {
      int cc = n0 * 16 + colb;
      float bv = biasc[cc];
#pragma unroll
      for (int j = 0; j < 4; ++j) {
        int rr = rb + j;
        if (rr < N_NODES) {
          float v = acc[mt][n0][j] + bv;
          if (OUT_RELU_BF16) {
            ((short*)outp)[(size_t)rr * 128 + cc] = f2bf(v > 0.f ? v : 0.f);
          } else {
            // layer-2 f32 output is never re-read: streaming store
            __builtin_nontemporal_store(v, (float*)outp + (size_t)rr * 128 + cc);
          }
        }
      }
    }
  }
}

extern "C" void kernel_launch(void* const* d_in, const int* in_sizes, int n_in,
                              void* d_out, int out_size, void* d_ws, size_t ws_size,
                              hipStream_t stream) {
  (void)in_sizes; (void)n_in; (void)out_size; (void)ws_size;
  const float* xq  = (const float*)d_in[0];
  const float* xp  = (const float*)d_in[1];
  const int*   src = (const int*)d_in[2];
  const int*   dst = (const int*)d_in[3];
  const float* Ws1 = (const float*)d_in[4];
  const float* Wn1 = (const float*)d_in[5];
  const float* b1  = (const float*)d_in[6];
  const float* Ws2 = (const float*)d_in[7];
  const float* Wn2 = (const float*)d_in[8];
  const float* b2  = (const float*)d_in[9];

  char* w = (char*)d_ws;
  int*   cnt    = (int*)w;      w += (size_t)4 * N_NODES * 4;
  int*   bincnt = (int*)w;      w += 4096;
  int*   off    = (int*)w;      w += (size_t)4 * (N_NODES + 1) * 4;
  int*   csr    = (int*)w;      w += (size_t)4 * NEDGE * 4;
  short* meanA  = (short*)w;    w += (size_t)N_NODES * 128 * 2;
  short* meanB  = (short*)w;    w += (size_t)N_NODES * 128 * 2;
  short* h1q    = (short*)w;    w += (size_t)N_NODES * 128 * 2;
  short* h1p    = (short*)w;    w += (size_t)N_NODES * 128 * 2;
  short* xqb    = (short*)w;    w += (size_t)N_NODES * 128 * 2;
  short* xpb    = (short*)w;    w += (size_t)N_NODES * 128 * 2;
  short* WTp    = (short*)w;    w += (size_t)4 * 49152 * 2;
  float* biasc  = (float*)w;    w += 512 * 4;
  int*   bsum   = (int*)w;      w += 4 * 128 * 4;
  // staging (packed u32) only live during CSR build, aliases meanA:
  unsigned* stage = (unsigned*)meanA;   // 4*196*3456*4B = 10.8MB <= 25.6MB
  // type-1 mean buffers alias dead storage (fully overwritten before read):
  unsigned* mL1C = (unsigned*)d_out;                 // L1: d_out is scratch
  unsigned* mL1D = mL1C + (size_t)N_NODES * 64;
  unsigned* mL2C = (unsigned*)xqb;                   // L2: xqb/xpb are dead
  unsigned* mL2D = (unsigned*)xpb;

  dim3 b256(256);
  const int bgrid = (NEDGE + 2047) / 2048;        // 293
  const int ggrid = (N_NODES + 127) / 128;        // 782
  const int wgrid = 2 * N_NODES / 4;              // 50000 (wave per node+type)
  const int cgrid = (N_NODES * 16 + 255) / 256;   // 6250

  // --- CSR build via bucket counting-sort (no per-edge global atomics)
  hipMemsetAsync(bincnt, 0, 4096, stream);
  bin_k<<<dim3(bgrid, 4), b256, 0, stream>>>(src, dst, bincnt, stage);
  hist_k<<<dim3(NBUCK, 4), b256, 0, stream>>>(stage, bincnt, cnt);
  scan1_k<<<dim3(NBLK, 4), b256, 0, stream>>>(cnt, bsum);
  scan2_k<<<dim3(1), dim3(128), 0, stream>>>(bsum);
  scan3_k<<<dim3(NBLK, 4), b256, 0, stream>>>(cnt, bsum, off);
  place_k<<<dim3(NBUCK, 4), b256, 0, stream>>>(stage, bincnt, off, csr);
  prep_w_k<<<dim3(384), b256, 0, stream>>>(Ws1, Wn1, Ws2, Wn2, WTp);
  prep_b_k<<<dim3(2), b256, 0, stream>>>(b1, b2, biasc);
  cvt2_k<<<dim3(cgrid, 2), b256, 0, stream>>>(xq, xp, (unsigned*)xqb, (unsigned*)xpb);

  // ---- Layer 1: one gather (both types), one gemm (both types)
  gather2_k<<<wgrid, b256, 0, stream>>>((const unsigned*)xpb, (const unsigned*)xqb,
      csr, off, (unsigned*)meanA, (unsigned*)meanB, mL1C, mL1D);
  gemm2_k<1><<<dim3(ggrid, 2), b256, 0, stream>>>(
      xqb, xpb, meanA, meanB, (const short*)mL1C, (const short*)mL1D,
      WTp, biasc, h1q, h1p);

  // ---- Layer 2
  gather2_k<<<wgrid, b256, 0, stream>>>((const unsigned*)h1p, (const unsigned*)h1q,
      csr, off, (unsigned*)meanA, (unsigned*)meanB, mL2C, mL2D);
  gemm2_k<0><<<dim3(ggrid, 2), b256, 0, stream>>>(
      h1q, h1p, meanA, meanB, (const short*)mL2C, (const short*)mL2D,
      WTp + 2 * 49152, biasc + 256,
      (float*)d_out, (float*)d_out + (size_t)N_NODES * 128);
}

// Round 11
// 471.334 us; speedup vs baseline: 1.0917x; 1.0917x over previous
//
#include <hip/hip_runtime.h>
#include <hip/hip_bf16.h>

#define N_NODES 100000
#define NEDGE   600000
#define SCAN_B  1024
#define NBLK    98            // ceil(N_NODES / SCAN_B)
#define BSHIFT  9             // bucket = dst >> 9 (512 nodes/bucket)
#define NBUCK   196           // ceil(N_NODES / 512)
#define BCAP    3456          // per (rel,bucket) staging cap (mean 3061 + 7 sigma)

typedef __attribute__((ext_vector_type(8))) short bf16x8;
typedef __attribute__((ext_vector_type(4))) short s16x4;
typedef __attribute__((ext_vector_type(4))) float f32x4;
typedef __attribute__((ext_vector_type(4))) unsigned u32x4;

__device__ __forceinline__ short f2bf(float f) {
  union { float f; unsigned u; } x; x.f = f;
  unsigned r = x.u + 0x7FFFu + ((x.u >> 16) & 1u);
  return (short)(r >> 16);
}

// Phase A: bin edges into 196 per-bucket segments. Packed entry:
// bits 0..16 = src (max 99999 < 2^17), bits 17..25 = dst & 511.
__global__ __launch_bounds__(256) void bin_k(const int* __restrict__ sidx,
                                             const int* __restrict__ didx,
                                             int* __restrict__ bincnt,
                                             unsigned* __restrict__ stage) {
  __shared__ int hist[NBUCK];
  __shared__ int base[NBUCK];
  int r = blockIdx.y, t = threadIdx.x;
  int e0 = blockIdx.x * 2048 + t;
  const int* dd = didx + (size_t)r * NEDGE;
  const int* ss = sidx + (size_t)r * NEDGE;
  for (int i = t; i < NBUCK; i += 256) hist[i] = 0;
  __syncthreads();
  unsigned pv[8]; int bu[8], lr[8];
#pragma unroll
  for (int j = 0; j < 8; ++j) {
    int e = e0 + j * 256;
    if (e < NEDGE) {
      int dv = dd[e];
      bu[j] = dv >> BSHIFT;
      pv[j] = (unsigned)ss[e] | ((unsigned)(dv & 511) << 17);
      lr[j] = atomicAdd(&hist[bu[j]], 1);     // LDS atomic
    }
  }
  __syncthreads();
  for (int i = t; i < NBUCK; i += 256)
    base[i] = atomicAdd(&bincnt[r * NBUCK + i], hist[i]);
  __syncthreads();
#pragma unroll
  for (int j = 0; j < 8; ++j) {
    int e = e0 + j * 256;
    if (e < NEDGE)
      stage[(size_t)(r * NBUCK + bu[j]) * BCAP + base[bu[j]] + lr[j]] = pv[j];
  }
}

// Phase B: one block per (bucket, rel): LDS histogram, coalesced cnt write.
__global__ __launch_bounds__(256) void hist_k(const unsigned* __restrict__ stage,
                                              const int* __restrict__ bincnt,
                                              int* __restrict__ cnt) {
  __shared__ int h[512];
  int bu = blockIdx.x, r = blockIdx.y, t = threadIdx.x;
  int len = bincnt[r * NBUCK + bu];
  const unsigned* sg = stage + (size_t)(r * NBUCK + bu) * BCAP;
  h[t] = 0; h[t + 256] = 0;
  __syncthreads();
  for (int i = t; i < len; i += 256) atomicAdd(&h[sg[i] >> 17], 1);  // LDS
  __syncthreads();
  int lo = bu << BSHIFT;
  int d0 = lo + t;
  if (d0 < N_NODES)       cnt[r * N_NODES + d0]       = h[t];
  if (d0 + 256 < N_NODES) cnt[r * N_NODES + d0 + 256] = h[t + 256];
}

__global__ __launch_bounds__(256) void scan1_k(const int* __restrict__ cnt,
                                               int* __restrict__ bsum) {
  __shared__ int lds[256];
  int b = blockIdx.x, r = blockIdx.y, t = threadIdx.x;
  int i0 = b * SCAN_B + t * 4;
  int s = 0;
#pragma unroll
  for (int j = 0; j < 4; ++j)
    if (i0 + j < N_NODES) s += cnt[r * N_NODES + i0 + j];
  lds[t] = s;
  __syncthreads();
  for (int st = 128; st > 0; st >>= 1) {
    if (t < st) lds[t] += lds[t + st];
    __syncthreads();
  }
  if (t == 0) bsum[r * NBLK + b] = lds[0];
}

__global__ __launch_bounds__(128) void scan2_k(int* __restrict__ bsum) {
  __shared__ int buf[128];
  int t = threadIdx.x;
  for (int r = 0; r < 4; ++r) {
    int v = (t < NBLK) ? bsum[r * NBLK + t] : 0;
    buf[t] = v;
    __syncthreads();
    for (int st = 1; st < 128; st <<= 1) {
      int x = (t >= st) ? buf[t - st] : 0;
      __syncthreads();
      buf[t] += x;
      __syncthreads();
    }
    if (t < NBLK) bsum[r * NBLK + t] = buf[t] - v;   // exclusive
    __syncthreads();
  }
}

__global__ __launch_bounds__(256) void scan3_k(const int* __restrict__ cnt,
                                               const int* __restrict__ bsum,
                                               int* __restrict__ off) {
  __shared__ int lds[256];
  int b = blockIdx.x, r = blockIdx.y, t = threadIdx.x;
  int i0 = b * SCAN_B + t * 4;
  int c[4] = {0, 0, 0, 0};
#pragma unroll
  for (int j = 0; j < 4; ++j)
    if (i0 + j < N_NODES) c[j] = cnt[r * N_NODES + i0 + j];
  int s = c[0] + c[1] + c[2] + c[3];
  lds[t] = s;
  __syncthreads();
  for (int st = 1; st < 256; st <<= 1) {
    int x = (t >= st) ? lds[t - st] : 0;
    __syncthreads();
    lds[t] += x;
    __syncthreads();
  }
  int run = bsum[r * NBLK + b] + lds[t] - s;
  int* o = off + r * (N_NODES + 1);
#pragma unroll
  for (int j = 0; j < 4; ++j) {
    if (i0 + j < N_NODES) { o[i0 + j] = run; run += c[j]; }
  }
  if (b == 0 && t == 0) o[N_NODES] = NEDGE;
}

// Phase C: one block per (bucket, rel): place edges with LDS-only cursors.
__global__ __launch_bounds__(256) void place_k(const unsigned* __restrict__ stage,
                                               const int* __restrict__ bincnt,
                                               const int* __restrict__ off,
                                               int* __restrict__ csr) {
  __shared__ int ofl[512];
  __shared__ int cur[512];
  int bu = blockIdx.x, r = blockIdx.y, t = threadIdx.x;
  int len = bincnt[r * NBUCK + bu];
  const unsigned* sg = stage + (size_t)(r * NBUCK + bu) * BCAP;
  const int* of = off + r * (N_NODES + 1);
  int* cs = csr + (size_t)r * NEDGE;
  int lo = bu << BSHIFT;
  int d0 = lo + t;
  ofl[t]       = (d0 < N_NODES) ? of[d0] : 0;
  ofl[t + 256] = (d0 + 256 < N_NODES) ? of[d0 + 256] : 0;
  cur[t] = 0; cur[t + 256] = 0;
  __syncthreads();
  for (int i = t; i < len; i += 256) {
    unsigned v = sg[i];
    int dl = v >> 17;
    int pos = ofl[dl] + atomicAdd(&cur[dl], 1);   // LDS atomic
    cs[pos] = (int)(v & 0x1FFFFu);
  }
}

// f32 -> packed bf16 for both inputs in one dispatch (blockIdx.y selects).
__global__ __launch_bounds__(256) void cvt2_k(const float* __restrict__ x0,
                                              const float* __restrict__ x1,
                                              unsigned* __restrict__ o0,
                                              unsigned* __restrict__ o1) {
  const float* x = blockIdx.y ? x1 : x0;
  unsigned* o = blockIdx.y ? o1 : o0;
  int i = blockIdx.x * 256 + threadIdx.x;     // i < N_NODES*16
  if (i >= N_NODES * 16) return;
  f32x4 v0 = ((const f32x4*)x)[i * 2];
  f32x4 v1 = ((const f32x4*)x)[i * 2 + 1];
  unsigned r0 = (unsigned)(unsigned short)f2bf(v0[0]) |
                ((unsigned)(unsigned short)f2bf(v0[1]) << 16);
  unsigned r1 = (unsigned)(unsigned short)f2bf(v0[2]) |
                ((unsigned)(unsigned short)f2bf(v0[3]) << 16);
  unsigned r2 = (unsigned)(unsigned short)f2bf(v1[0]) |
                ((unsigned)(unsigned short)f2bf(v1[1]) << 16);
  unsigned r3 = (unsigned)(unsigned short)f2bf(v1[2]) |
                ((unsigned)(unsigned short)f2bf(v1[3]) << 16);
  ((u32x4*)o)[i] = (u32x4){r0, r1, r2, r3};
}

// Pack combined weights into MFMA B-fragment-linear layout.
__global__ __launch_bounds__(256) void prep_w_k(const float* __restrict__ Ws1,
                                                const float* __restrict__ Wn1,
                                                const float* __restrict__ Ws2,
                                                const float* __restrict__ Wn2,
                                                short* __restrict__ WTp) {
  int tid = blockIdx.x * 256 + threadIdx.x;  // 0..98303
  int lane = tid & 63;
  int n0 = (tid >> 6) & 7;
  int idx3 = tid >> 9;
  int k0 = idx3 % 12;
  int lt = idx3 / 12;
  int l = lt >> 1, t = lt & 1;
  const float* Wself  = l ? Ws2 : Ws1;
  const float* Wneigh = l ? Wn2 : Wn1;
  int rA = t ? 0 : 1, rB = t ? 3 : 2;
  int n = n0 * 16 + (lane & 15);
  int kbase = k0 * 32 + (lane >> 4) * 8;
  short out[8];
#pragma unroll
  for (int j = 0; j < 8; ++j) {
    int k = kbase + j;
    int kk = k & 127, blk = k >> 7;
    float v;
    if (blk == 0)      v = Wself[rA * 16384 + kk * 128 + n] + Wself[rB * 16384 + kk * 128 + n];
    else if (blk == 1) v = Wneigh[rA * 16384 + kk * 128 + n];
    else               v = Wneigh[rB * 16384 + kk * 128 + n];
    out[j] = f2bf(v);
  }
  s16x4* dst = (s16x4*)&WTp[tid * 8];
  dst[0] = *(s16x4*)&out[0];
  dst[1] = *(s16x4*)&out[4];
}

__global__ __launch_bounds__(256) void prep_b_k(const float* __restrict__ b1,
                                                const float* __restrict__ b2,
                                                float* __restrict__ biasc) {
  int tid = blockIdx.x * 256 + threadIdx.x;
  if (tid >= 512) return;
  int l = tid >> 8, t = (tid >> 7) & 1, c = tid & 127;
  const float* b = l ? b2 : b1;
  int rA = t ? 0 : 1, rB = t ? 3 : 2;
  biasc[tid] = b[rA * 128 + c] + b[rB * 128 + c];
}

#define ACC8(u, a)                                            \
  {                                                           \
    _Pragma("unroll") for (int q = 0; q < 4; ++q) {           \
      union { unsigned w; float f; } lo_, hi_;                \
      lo_.w = (u)[q] << 16; hi_.w = (u)[q] & 0xffff0000u;     \
      (a)[2 * q] += lo_.f; (a)[2 * q + 1] += hi_.f;           \
    }                                                         \
  }

__device__ __forceinline__ int clampi(int q, int p0, int p1) {
  int t = q < p1 ? q : p0;
  return t < NEDGE ? t : 0;
}

// One wave per node handling BOTH relations; both node types in one dispatch.
__global__ __launch_bounds__(256) void gather2_k(
    const unsigned* __restrict__ src0, const unsigned* __restrict__ src1,
    const int* __restrict__ csr, const int* __restrict__ off,
    unsigned* __restrict__ m00, unsigned* __restrict__ m01,
    unsigned* __restrict__ m10, unsigned* __restrict__ m11) {
  int wv = __builtin_amdgcn_readfirstlane(threadIdx.x >> 6);
  int wid = blockIdx.x * 4 + wv;          // 0 .. 2*N_NODES-1
  int lane = threadIdx.x & 63;
  int type = wid >= N_NODES;
  int n = type ? wid - N_NODES : wid;
  const unsigned* src = type ? src1 : src0;
  const int* csrA = csr + (type ? 0 : 1) * NEDGE;
  const int* csrB = csr + (type ? 3 : 2) * NEDGE;
  const int* offA = off + (type ? 0 : 1) * (N_NODES + 1);
  const int* offB = off + (type ? 3 : 2) * (N_NODES + 1);
  unsigned* mA = type ? m10 : m00;
  unsigned* mB = type ? m11 : m01;
  int pA0 = offA[n], pA1 = offA[n + 1];
  int pB0 = offB[n], pB1 = offB[n + 1];
  int degA = pA1 - pA0, degB = pB1 - pB0;
  int rowg = lane >> 4;          // 0..3: row within each quad
  int colg = lane & 15;          // 16B slice: u32s colg*4 .. colg*4+3
  float a[8] = {}, b[8] = {};
  // fast path: first 8 edges of each relation, all loads issued up front
  {
    int ia0 = csrA[clampi(pA0 + rowg,     pA0, pA1)];
    int ia1 = csrA[clampi(pA0 + 4 + rowg, pA0, pA1)];
    int ib0 = csrB[clampi(pB0 + rowg,     pB0, pB1)];
    int ib1 = csrB[clampi(pB0 + 4 + rowg, pB0, pB1)];
    u32x4 ua0 = *(const u32x4*)(src + (size_t)ia0 * 64 + colg * 4);
    u32x4 ua1 = *(const u32x4*)(src + (size_t)ia1 * 64 + colg * 4);
    u32x4 ub0 = *(const u32x4*)(src + (size_t)ib0 * 64 + colg * 4);
    u32x4 ub1 = *(const u32x4*)(src + (size_t)ib1 * 64 + colg * 4);
    if (pA0 + rowg     < pA1) ACC8(ua0, a);
    if (pA0 + 4 + rowg < pA1) ACC8(ua1, a);
    if (pB0 + rowg     < pB1) ACC8(ub0, b);
    if (pB0 + 4 + rowg < pB1) ACC8(ub1, b);
  }
  for (int p = pA0 + 8; p < pA1; p += 8) {
    int i0 = csrA[clampi(p + rowg,     pA0, pA1)];
    int i1 = csrA[clampi(p + 4 + rowg, pA0, pA1)];
    u32x4 u0 = *(const u32x4*)(src + (size_t)i0 * 64 + colg * 4);
    u32x4 u1 = *(const u32x4*)(src + (size_t)i1 * 64 + colg * 4);
    if (p + rowg     < pA1) ACC8(u0, a);
    if (p + 4 + rowg < pA1) ACC8(u1, a);
  }
  for (int p = pB0 + 8; p < pB1; p += 8) {
    int i0 = csrB[clampi(p + rowg,     pB0, pB1)];
    int i1 = csrB[clampi(p + 4 + rowg, pB0, pB1)];
    u32x4 u0 = *(const u32x4*)(src + (size_t)i0 * 64 + colg * 4);
    u32x4 u1 = *(const u32x4*)(src + (size_t)i1 * 64 + colg * 4);
    if (p + rowg     < pB1) ACC8(u0, b);
    if (p + 4 + rowg < pB1) ACC8(u1, b);
  }
#pragma unroll
  for (int q = 0; q < 8; ++q) {
    a[q] += __shfl_xor(a[q], 16); a[q] += __shfl_xor(a[q], 32);
    b[q] += __shfl_xor(b[q], 16); b[q] += __shfl_xor(b[q], 32);
  }
  if (rowg == 0) {
    float invA = 1.0f / (float)(degA > 1 ? degA : 1);
    float invB = 1.0f / (float)(degB > 1 ? degB : 1);
    u32x4 wa, wb;
#pragma unroll
    for (int q = 0; q < 4; ++q) {
      wa[q] = (unsigned)(unsigned short)f2bf(a[2 * q] * invA) |
              ((unsigned)(unsigned short)f2bf(a[2 * q + 1] * invA) << 16);
      wb[q] = (unsigned)(unsigned short)f2bf(b[2 * q] * invB) |
              ((unsigned)(unsigned short)f2bf(b[2 * q + 1] * invB) << 16);
    }
    // regular stores: means are re-read by the gemm — keep them in L2.
    *(u32x4*)(mA + (size_t)n * 64 + colg * 4) = wa;
    *(u32x4*)(mB + (size_t)n * 64 + colg * 4) = wb;
  }
}

// LDS-staged GEMM, 32KB LDS (3 chunks of 4 k-steps) -> 5 blocks/CU so the
// per-barrier drain is hidden by other resident blocks (r9's 48KB gave 3).
template<int OUT_RELU_BF16>
__global__ __launch_bounds__(256) void gemm2_k(
    const short* __restrict__ self0, const short* __restrict__ self1,
    const short* __restrict__ mA0, const short* __restrict__ mB0,
    const short* __restrict__ mA1, const short* __restrict__ mB1,
    const short* __restrict__ WTpL, const float* __restrict__ biascL,
    void* __restrict__ out0, void* __restrict__ out1) {
  __shared__ short Wlds[4 * 8 * 512];   // 32KB: 4 k-steps of B-fragments
  int type = blockIdx.y;
  const short* selfp = type ? self1 : self0;
  const short* meanA = type ? mA1 : mA0;
  const short* meanB = type ? mB1 : mB0;
  const short* WTp = WTpL + type * 49152;
  const float* biasc = biascL + type * 128;
  void* outp = type ? out1 : out0;
  int tid = threadIdx.x;
  int lane = tid & 63, wave = tid >> 6;
  int rowbase = blockIdx.x * 128 + wave * 32;
  int r0 = rowbase + (lane & 15), r1 = r0 + 16;
  int rc0 = r0 < N_NODES ? r0 : N_NODES - 1;
  int rc1 = r1 < N_NODES ? r1 : N_NODES - 1;
  int kg = lane >> 4;
  f32x4 acc[2][8] = {};
  for (int ch = 0; ch < 3; ++ch) {
    __syncthreads();
    const f32x4* s = (const f32x4*)WTp + ch * 2048;
    f32x4* dst = (f32x4*)Wlds;
#pragma unroll
    for (int i = 0; i < 8; ++i) dst[tid + i * 256] = s[tid + i * 256];
    __syncthreads();
    // chunk ch holds k-steps 4ch..4ch+3; the A-operand array switches at
    // chunk boundaries (ch0=self, ch1=meanA, ch2=meanB).
    const short* mp = (ch == 0) ? selfp : ((ch == 1) ? meanA : meanB);
#pragma unroll
    for (int kh = 0; kh < 4; ++kh) {
      int kin = kh * 32 + kg * 8;
      bf16x8 a0 = *(const bf16x8*)(mp + (size_t)rc0 * 128 + kin);
      bf16x8 a1 = *(const bf16x8*)(mp + (size_t)rc1 * 128 + kin);
      const short* wb = &Wlds[kh * 4096 + lane * 8];
#pragma unroll
      for (int n0 = 0; n0 < 8; ++n0) {
        bf16x8 b = *(const bf16x8*)(wb + n0 * 512);
        acc[0][n0] = __builtin_amdgcn_mfma_f32_16x16x32_bf16(a0, b, acc[0][n0], 0, 0, 0);
        acc[1][n0] = __builtin_amdgcn_mfma_f32_16x16x32_bf16(a1, b, acc[1][n0], 0, 0, 0);
      }
    }
  }
  int colb = lane & 15, rloc = kg * 4;
#pragma unroll
  for (int mt = 0; mt < 2; ++mt) {
    int rb = rowbase + mt * 16 + rloc;
#pragma unroll
    for (int n0 = 0; n0 < 8; ++n0) {
      int cc = n0 * 16 + colb;
      float bv = biasc[cc];
#pragma unroll
      for (int j = 0; j < 4; ++j) {
        int rr = rb + j;
        if (rr < N_NODES) {
          float v = acc[mt][n0][j] + bv;
          if (OUT_RELU_BF16) {
            ((short*)outp)[(size_t)rr * 128 + cc] = f2bf(v > 0.f ? v : 0.f);
          } else {
            // final f32 output: true streaming write, never re-read on GPU
            __builtin_nontemporal_store(v, (float*)outp + (size_t)rr * 128 + cc);
          }
        }
      }
    }
  }
}

extern "C" void kernel_launch(void* const* d_in, const int* in_sizes, int n_in,
                              void* d_out, int out_size, void* d_ws, size_t ws_size,
                              hipStream_t stream) {
  (void)in_sizes; (void)n_in; (void)out_size; (void)ws_size;
  const float* xq  = (const float*)d_in[0];
  const float* xp  = (const float*)d_in[1];
  const int*   src = (const int*)d_in[2];
  const int*   dst = (const int*)d_in[3];
  const float* Ws1 = (const float*)d_in[4];
  const float* Wn1 = (const float*)d_in[5];
  const float* b1  = (const float*)d_in[6];
  const float* Ws2 = (const float*)d_in[7];
  const float* Wn2 = (const float*)d_in[8];
  const float* b2  = (const float*)d_in[9];

  char* w = (char*)d_ws;
  int*   cnt    = (int*)w;      w += (size_t)4 * N_NODES * 4;
  int*   bincnt = (int*)w;      w += 4096;
  int*   off    = (int*)w;      w += (size_t)4 * (N_NODES + 1) * 4;
  int*   csr    = (int*)w;      w += (size_t)4 * NEDGE * 4;
  short* meanA  = (short*)w;    w += (size_t)N_NODES * 128 * 2;
  short* meanB  = (short*)w;    w += (size_t)N_NODES * 128 * 2;
  short* h1q    = (short*)w;    w += (size_t)N_NODES * 128 * 2;
  short* h1p    = (short*)w;    w += (size_t)N_NODES * 128 * 2;
  short* xqb    = (short*)w;    w += (size_t)N_NODES * 128 * 2;
  short* xpb    = (short*)w;    w += (size_t)N_NODES * 128 * 2;
  short* WTp    = (short*)w;    w += (size_t)4 * 49152 * 2;
  float* biasc  = (float*)w;    w += 512 * 4;
  int*   bsum   = (int*)w;      w += 4 * 128 * 4;
  // staging (packed u32) only live during CSR build, aliases meanA:
  unsigned* stage = (unsigned*)meanA;   // 4*196*3456*4B = 10.8MB <= 25.6MB
  // type-1 mean buffers alias dead storage (fully overwritten before read):
  unsigned* mL1C = (unsigned*)d_out;                 // L1: d_out is scratch
  unsigned* mL1D = mL1C + (size_t)N_NODES * 64;
  unsigned* mL2C = (unsigned*)xqb;                   // L2: xqb/xpb are dead
  unsigned* mL2D = (unsigned*)xpb;

  dim3 b256(256);
  const int bgrid = (NEDGE + 2047) / 2048;        // 293
  const int ggrid = (N_NODES + 127) / 128;        // 782
  const int wgrid = 2 * N_NODES / 4;              // 50000 (wave per node+type)
  const int cgrid = (N_NODES * 16 + 255) / 256;   // 6250

  // --- CSR build via bucket counting-sort (no per-edge global atomics)
  hipMemsetAsync(bincnt, 0, 4096, stream);
  bin_k<<<dim3(bgrid, 4), b256, 0, stream>>>(src, dst, bincnt, stage);
  hist_k<<<dim3(NBUCK, 4), b256, 0, stream>>>(stage, bincnt, cnt);
  scan1_k<<<dim3(NBLK, 4), b256, 0, stream>>>(cnt, bsum);
  scan2_k<<<dim3(1), dim3(128), 0, stream>>>(bsum);
  scan3_k<<<dim3(NBLK, 4), b256, 0, stream>>>(cnt, bsum, off);
  place_k<<<dim3(NBUCK, 4), b256, 0, stream>>>(stage, bincnt, off, csr);
  prep_w_k<<<dim3(384), b256, 0, stream>>>(Ws1, Wn1, Ws2, Wn2, WTp);
  prep_b_k<<<dim3(2), b256, 0, stream>>>(b1, b2, biasc);
  cvt2_k<<<dim3(cgrid, 2), b256, 0, stream>>>(xq, xp, (unsigned*)xqb, (unsigned*)xpb);

  // ---- Layer 1: one gather (both types), one gemm (both types)
  gather2_k<<<wgrid, b256, 0, stream>>>((const unsigned*)xpb, (const unsigned*)xqb,
      csr, off, (unsigned*)meanA, (unsigned*)meanB, mL1C, mL1D);
  gemm2_k<1><<<dim3(ggrid, 2), b256, 0, stream>>>(
      xqb, xpb, meanA, meanB, (const short*)mL1C, (const short*)mL1D,
      WTp, biasc, h1q, h1p);

  // ---- Layer 2
  gather2_k<<<wgrid, b256, 0, stream>>>((const unsigned*)h1p, (const unsigned*)h1q,
      csr, off, (unsigned*)meanA, (unsigned*)meanB, mL2C, mL2D);
  gemm2_k<0><<<dim3(ggrid, 2), b256, 0, stream>>>(
      h1q, h1p, meanA, meanB, (const short*)mL2C, (const short*)mL2D,
      WTp + 2 * 49152, biasc + 256,
      (float*)d_out, (float*)d_out + (size_t)N_NODES * 128);
}